// Round 4
// baseline (238.147 us; speedup 1.0000x reference)
//
#include <hip/hip_runtime.h>

// CSConv2D: per-pixel kernel selection from a 25-entry 5x5 bank, depthwise,
// 'same' zero pad. B=8, C=96, H=W=192, fp32.
//
// Structure (R2/R3): vertical register blocking — each thread computes 4
// output rows of one column; each staged input row-segment (5 floats) feeds
// up to 4 accumulators, so LDS tap-reads are 10 dwords/output. Weights for
// the 4 rows (4 buckets x 25) are gathered once per block (channel-invariant)
// into 100 VGPRs.
//
// R4 fix: R3 shipped with VGPR_Count=76 — the compiler REMATERIALIZED the
// weight reads from LDS inside the c-loop instead of keeping wreg live
// (~35 LDS dwords/output -> LDS-pipe bound at ~102us). The empty inline-asm
// "+v" constraint below makes each weight value opaque, forcing it to stay
// in a VGPR across the loop. Expect VGPR ~140-168 and ~2x speedup.

#define KS 5
#define NB 25
#define HALO 2
#define TH 8                    // output rows per block
#define RPT 4                   // output rows per thread
#define WID 192
#define HEI 192
#define CH 96
#define NBATCH 8
#define LROW (WID + 2 * HALO)   // 196 floats per LDS row
#define LH (TH + 2 * HALO)      // 12 staged rows
#define CSPLIT 4
#define CPB (CH / CSPLIT)       // 24 channels per block
#define NTHREADS (WID * (TH / RPT))  // 384 threads = 6 waves
#define SLOTS_PER_THREAD 3      // 12 rows * 96 float2 slots / 384 threads

__global__ __launch_bounds__(NTHREADS, 3) void csconv_kernel(
    const float* __restrict__ in, const float* __restrict__ bank,
    const int* __restrict__ buckets, float* __restrict__ out)
{
    __shared__ float sb[NB * KS * KS];        // 625 floats: whole kernel bank
    __shared__ float sin_[2][LH][LROW];       // double-buffered input slab

    const int tid  = threadIdx.x;
    const int wcol = tid % WID;     // 0..191
    const int ty   = tid / WID;     // 0..1 (thread-row group)
    const int cg   = blockIdx.x;    // channel group 0..3
    const int ht   = blockIdx.y;    // row tile 0..23
    const int b    = blockIdx.z;    // batch 0..7
    const int h0   = ht * TH;
    const int r0   = h0 + ty * RPT; // first output row this thread owns

    // Stage kernel bank into LDS (2.5 KB, once per block). 625 > NTHREADS:
    // strided loop required.
    for (int t = tid; t < NB * KS * KS; t += NTHREADS) sb[t] = bank[t];
    // Zero the W-halo pad columns (0,1,194,195) of both buffers once; the
    // channel staging only writes cols 2..193, so the pad persists.
    if (tid < 2 * LH * 4) {
        int buf = tid / (LH * 4);
        int r   = (tid / 4) % LH;
        int p   = tid & 3;
        int col = (p < 2) ? p : (WID + HALO + (p - 2));
        sin_[buf][r][col] = 0.0f;
    }
    __syncthreads();

    // Per-pixel weight gather: channel-invariant, once per block. 4 rows =>
    // 4 buckets => 100 weight registers per thread.
    float wreg[RPT][NB];
#pragma unroll
    for (int r = 0; r < RPT; ++r) {
        const int bkt = buckets[(b * HEI + r0 + r) * WID + wcol];
#pragma unroll
        for (int t = 0; t < NB; ++t) wreg[r][t] = sb[bkt * NB + t];
    }
    // Pin every weight into a VGPR: the asm result is opaque, so the
    // compiler cannot rematerialize the LDS loads inside the c-loop.
#pragma unroll
    for (int r = 0; r < RPT; ++r)
#pragma unroll
        for (int t = 0; t < NB; ++t)
            asm("" : "+v"(wreg[r][t]));

    const int c0 = cg * CPB;
    const float* inb  = in  + (size_t)(b * CH + c0) * (HEI * WID);
    float*       outb = out + (size_t)(b * CH + c0) * (HEI * WID);

    // Staging map: 12 rows x 96 float2 = 1152 slots; thread t owns slots
    // t, t+384, t+768 -> same column pair, staged rows (t/96) + {0,4,8}.
    const int srow0 = tid / (WID / 2);         // 0..3
    const int scol  = (tid % (WID / 2)) * 2;   // even column 0..190
    bool row_ok[SLOTS_PER_THREAD];
    const float* srcp[SLOTS_PER_THREAD];
#pragma unroll
    for (int k = 0; k < SLOTS_PER_THREAD; ++k) {
        const int srow = srow0 + 4 * k;
        const int hg   = h0 - HALO + srow;
        row_ok[k] = (hg >= 0) && (hg < HEI);
        srcp[k]   = inb + (size_t)hg * WID + scol;   // deref only if row_ok
    }

    // Prologue: stage c=0 into buffer 0.
#pragma unroll
    for (int k = 0; k < SLOTS_PER_THREAD; ++k) {
        float2 v = make_float2(0.0f, 0.0f);
        if (row_ok[k]) v = *(const float2*)srcp[k];
        *(float2*)&sin_[0][srow0 + 4 * k][scol + HALO] = v;
    }
    __syncthreads();

    const int ty4 = ty * RPT;
    for (int c = 0; c < CPB; ++c) {
        const int cur = c & 1;
        // Issue next channel's staging loads early; consume (ds_write) after
        // the conv so the VMEM latency is covered by compute.
        float2 v[SLOTS_PER_THREAD];
        const bool has_next = (c + 1 < CPB);
        if (has_next) {
            const size_t coff = (size_t)(c + 1) * (HEI * WID);
#pragma unroll
            for (int k = 0; k < SLOTS_PER_THREAD; ++k) {
                v[k] = make_float2(0.0f, 0.0f);
                if (row_ok[k]) v[k] = *(const float2*)(srcp[k] + coff);
            }
        }

        // Conv: 8 staged rows feed 4 vertically-adjacent outputs.
        float acc[RPT] = {0.0f, 0.0f, 0.0f, 0.0f};
#pragma unroll
        for (int i = 0; i < TH; ++i) {
            const float* rowp = &sin_[cur][ty4 + i][wcol];
            const float x0 = rowp[0], x1 = rowp[1], x2 = rowp[2],
                        x3 = rowp[3], x4 = rowp[4];
#pragma unroll
            for (int r = 0; r < RPT; ++r) {
                const int ki = i - r;
                if (ki >= 0 && ki < KS) {   // compile-time after unroll
                    const float* w = &wreg[r][ki * KS];
                    acc[r] += x0 * w[0] + x1 * w[1] + x2 * w[2]
                            + x3 * w[3] + x4 * w[4];
                }
            }
        }

        if (has_next) {
#pragma unroll
            for (int k = 0; k < SLOTS_PER_THREAD; ++k)
                *(float2*)&sin_[cur ^ 1][srow0 + 4 * k][scol + HALO] = v[k];
        }

#pragma unroll
        for (int r = 0; r < RPT; ++r)
            outb[((size_t)c * HEI + r0 + r) * WID + wcol] = acc[r];

        __syncthreads();
    }
}

extern "C" void kernel_launch(void* const* d_in, const int* in_sizes, int n_in,
                              void* d_out, int out_size, void* d_ws, size_t ws_size,
                              hipStream_t stream) {
    const float* in      = (const float*)d_in[0];
    const float* bank    = (const float*)d_in[1];
    const int*   buckets = (const int*)d_in[2];
    float*       out     = (float*)d_out;
    dim3 grid(CSPLIT, HEI / TH, NBATCH);
    csconv_kernel<<<grid, NTHREADS, 0, stream>>>(in, bank, buckets, out);
}